// Round 14
// baseline (367.851 us; speedup 1.0000x reference)
//
#include <hip/hip_runtime.h>
#include <math.h>

#define N_NODES 100000
#define S1 50
#define S2 10
#define HID 128
#define NT 64          // nodes per block in enc2_mlp
#define AST 66         // act row stride in doubles ([k][n] rows, 16B-aligned)
#define SM_BLOCKS 196  // softmax persistent blocks (<=256 -> all co-resident)

// transposed fp64 weight sizes
#define W2_ELEMS   (128 * 128)     // Wt2[k][o]
#define WA_ELEMS   (129 * 128)     // Wta[k][o], k=128 row = remaining-space col
#define WB_ELEMS   (128 * 64)      // Wtb[k][o]
#define PAD_ELEMS  (W2_ELEMS + WA_ELEMS + WB_ELEMS)   // 41088

// monotone u64 key for fp64 atomicMax (finite doubles)
__device__ __forceinline__ unsigned long long dkey(double d) {
    unsigned long long u = __double_as_longlong(d);
    return (u & 0x8000000000000000ULL) ? ~u : (u | 0x8000000000000000ULL);
}
__device__ __forceinline__ double dunkey(unsigned long long k) {
    return (k & 0x8000000000000000ULL)
        ? __longlong_as_double(k & 0x7FFFFFFFFFFFFFFFULL)
        : __longlong_as_double(~k);
}

// ---------------- kernel 0: weight transpose + feat->float4 pack + scalar init
__global__ __launch_bounds__(256) void pack_kernel(
    const float* __restrict__ feat,
    const float* __restrict__ W2, const float* __restrict__ w_a,
    const float* __restrict__ w_b,
    double* __restrict__ wt, float4* __restrict__ feat4,
    unsigned long long* __restrict__ gmaxu, double* __restrict__ gsum,
    int* __restrict__ done)
{
    int i = blockIdx.x * 256 + threadIdx.x;
    if (i == 0) { gmaxu[0] = 0ULL; gsum[0] = 0.0; done[0] = 0; }
    if (i < W2_ELEMS) {
        int k = i >> 7, o = i & 127;
        wt[i] = (double)W2[o * 128 + k];
    } else if (i < W2_ELEMS + WA_ELEMS) {
        int j = i - W2_ELEMS;
        int k = j >> 7, o = j & 127;
        wt[i] = (double)w_a[o * 129 + k];
    } else if (i < PAD_ELEMS) {
        int j = i - W2_ELEMS - WA_ELEMS;
        int k = j >> 6, o = j & 63;
        wt[i] = (double)w_b[o * 128 + k];
    } else if (i < PAD_ELEMS + N_NODES) {
        int n = i - PAD_ELEMS;
        float4 v = { feat[n * 3 + 0], feat[n * 3 + 1], feat[n * 3 + 2], 0.0f };
        feat4[n] = v;
    }
}

// ---------------- kernel 1: agg1 (fp64), one node per thread.
// r26: index loads vectorized to int2 (row base 200n is 8B-aligned) --
// 25 divergent index instructions per wave instead of 50.
__global__ __launch_bounds__(64) void gather_kernel(
    const float4* __restrict__ feat4, const int* __restrict__ neigh1,
    double* __restrict__ agg1d)
{
    const int n = blockIdx.x * 64 + threadIdx.x;
    if (n >= N_NODES) return;
    const int2* __restrict__ row2 = (const int2*)&neigh1[n * S1];
    double f0, f1, f2;
    { float4 v = feat4[n]; f0 = (double)v.x; f1 = (double)v.y; f2 = (double)v.z; }
    #pragma unroll 5
    for (int j = 0; j < S1 / 2; j++) {
        int2 p = row2[j];
        float4 a = feat4[p.x];
        float4 b = feat4[p.y];
        f0 += (double)a.x + (double)b.x;
        f1 += (double)a.y + (double)b.y;
        f2 += (double)a.z + (double)b.z;
    }
    const double r51 = 1.0 / 51.0;
    agg1d[n * 3 + 0] = f0 * r51;
    agg1d[n * 3 + 1] = f1 * r51;
    agg1d[n * 3 + 2] = f2 * r51;
}

// ---------------- kernel 2: enc2 + MLP + score, fp64, software-pipelined.
// FROZEN at r23 (268 us measured; the per-thread hot-loop core is the
// r15 shape that six structural variants failed to beat).
__global__ __launch_bounds__(256, 1) void enc2_mlp_kernel(
    const int* __restrict__ nodes, const int* __restrict__ neigh2,
    const double* __restrict__ agg1d,
    const float* __restrict__ W1, const double* __restrict__ wt,
    const float* __restrict__ b_a, const float* __restrict__ b_b,
    const float* __restrict__ w_c, const float* __restrict__ b_c,
    const int* __restrict__ psz, const int* __restrict__ npe,
    double* __restrict__ scoresd, unsigned long long* __restrict__ gmaxu)
{
    __shared__ __align__(16) double sX[HID * AST];      // 67584 B, acts [k][n]
    __shared__ double sS[4];
    double* sG = sX;   // gathered agg1 rows, NT*11*4 = 2816 doubles (22528 B),
                       // aliases sX rows 0..42 -- dead before first sX write

    const double* __restrict__ Wt2 = wt;
    const double* __restrict__ Wta = wt + W2_ELEMS;
    const double* __restrict__ Wtb = wt + W2_ELEMS + WA_ELEMS;

    const int tid  = threadIdx.x;
    const int base = blockIdx.x * NT;               // 1563 blocks, last partial

    // ---- phase 0: gather 11 agg1 rows per node into sG (704 items)
    for (int t = tid; t < NT * (S2 + 1); t += 256) {
        int ns = t / 11, j = t - ns * 11;
        int gi = base + ns;
        int node = nodes[gi < N_NODES ? gi : N_NODES - 1];  // tail clamp
        int src  = (j == 0) ? node : neigh2[node * S2 + (j - 1)];
        sG[t * 4 + 0] = agg1d[src * 3 + 0];
        sG[t * 4 + 1] = agg1d[src * 3 + 1];
        sG[t * 4 + 2] = agg1d[src * 3 + 2];
    }
    __syncthreads();

    // ---- phase 1: agg2[t][n] = mean_j relu(W1[t].row_j) -> sX[t*AST+n]
    {
        const int n = tid & 63;
        double g0[11], g1[11], g2[11];
        #pragma unroll
        for (int j = 0; j < 11; j++) {
            g0[j] = sG[(n * 11 + j) * 4 + 0];
            g1[j] = sG[(n * 11 + j) * 4 + 1];
            g2[j] = sG[(n * 11 + j) * 4 + 2];
        }
        __syncthreads();   // sG fully consumed into registers; sX may be written
        const int part = tid >> 6;                  // 0..3
        #pragma unroll
        for (int s = 0; s < 32; s++) {
            int t = part * 32 + s;
            double wx = (double)W1[t * 3 + 0];
            double wy = (double)W1[t * 3 + 1];
            double wz = (double)W1[t * 3 + 2];
            double acc = 0.0;
            #pragma unroll
            for (int j = 0; j < 11; j++)
                acc += fmax(wx * g0[j] + wy * g1[j] + wz * g2[j], 0.0);
            sX[t * AST + n] = acc / 11.0;
        }
    }
    __syncthreads();

    const int og = tid & 31;          // 0..31
    const int ng = tid >> 5;          // 0..7
    const int n0 = 8 * ng;            // 8 node cols per thread (64 total)
    const int o0 = 2 * og;            // outs o0, o0+1, 64+o0, 64+o0+1

    // ---- phase 2: emb = relu(W2 @ agg2), in-place sX
    {
        double acc[4][8] = {};
        const double* __restrict__ wk = &Wt2[o0];
        const double* __restrict__ ak = &sX[n0];
        // pipeline primers: weights k=0 (current) and k=1 (next); acts k=0
        double2 wc0 = *(const double2*)&wk[0];
        double2 wc1 = *(const double2*)&wk[64];
        double2 wd0 = *(const double2*)&wk[128];
        double2 wd1 = *(const double2*)&wk[128 + 64];
        double2 ac[4];
        #pragma unroll
        for (int i = 0; i < 4; i++) ac[i] = *(const double2*)&ak[2 * i];
        #pragma unroll 4
        for (int k = 0; k < 128; k++) {
            const int k1 = (k + 1) & 127;
            const int k2 = (k + 2) & 127;
            double2 wn0 = *(const double2*)&wk[k2 * 128];
            double2 wn1 = *(const double2*)&wk[k2 * 128 + 64];
            double2 an[4];
            #pragma unroll
            for (int i = 0; i < 4; i++)
                an[i] = *(const double2*)&ak[k1 * AST + 2 * i];
            #pragma unroll
            for (int i = 0; i < 4; i++) {
                acc[0][2*i]   += wc0.x * ac[i].x; acc[0][2*i+1] += wc0.x * ac[i].y;
                acc[1][2*i]   += wc0.y * ac[i].x; acc[1][2*i+1] += wc0.y * ac[i].y;
                acc[2][2*i]   += wc1.x * ac[i].x; acc[2][2*i+1] += wc1.x * ac[i].y;
                acc[3][2*i]   += wc1.y * ac[i].x; acc[3][2*i+1] += wc1.y * ac[i].y;
            }
            wc0 = wd0; wc1 = wd1; wd0 = wn0; wd1 = wn1;
            #pragma unroll
            for (int i = 0; i < 4; i++) ac[i] = an[i];
        }
        __syncthreads();   // all reads of sX done
        #pragma unroll
        for (int i = 0; i < 4; i++) {
            int o = (i < 2) ? (o0 + i) : (64 + o0 + i - 2);
            #pragma unroll
            for (int j = 0; j < 4; j++) {
                double2 v = { fmax(acc[i][2*j], 0.0), fmax(acc[i][2*j+1], 0.0) };
                *(double2*)&sX[o * AST + n0 + 2 * j] = v;
            }
        }
    }
    __syncthreads();

    // ---- phase 3: xa = relu(w_a[:,:128] @ emb + w_a[:,128]*rem + b_a), in-place
    {
        double acc[4][8] = {};
        const double* __restrict__ wk = &Wta[o0];
        const double* __restrict__ ak = &sX[n0];
        double2 wc0 = *(const double2*)&wk[0];
        double2 wc1 = *(const double2*)&wk[64];
        double2 wd0 = *(const double2*)&wk[128];
        double2 wd1 = *(const double2*)&wk[128 + 64];
        double2 ac[4];
        #pragma unroll
        for (int i = 0; i < 4; i++) ac[i] = *(const double2*)&ak[2 * i];
        #pragma unroll 4
        for (int k = 0; k < 128; k++) {
            const int k1 = (k + 1) & 127;
            const int k2 = (k + 2) & 127;
            double2 wn0 = *(const double2*)&wk[k2 * 128];
            double2 wn1 = *(const double2*)&wk[k2 * 128 + 64];
            double2 an[4];
            #pragma unroll
            for (int i = 0; i < 4; i++)
                an[i] = *(const double2*)&ak[k1 * AST + 2 * i];
            #pragma unroll
            for (int i = 0; i < 4; i++) {
                acc[0][2*i]   += wc0.x * ac[i].x; acc[0][2*i+1] += wc0.x * ac[i].y;
                acc[1][2*i]   += wc0.y * ac[i].x; acc[1][2*i+1] += wc0.y * ac[i].y;
                acc[2][2*i]   += wc1.x * ac[i].x; acc[2][2*i+1] += wc1.x * ac[i].y;
                acc[3][2*i]   += wc1.y * ac[i].x; acc[3][2*i+1] += wc1.y * ac[i].y;
            }
            wc0 = wd0; wc1 = wd1; wd0 = wn0; wd1 = wn1;
            #pragma unroll
            for (int i = 0; i < 4; i++) ac[i] = an[i];
        }
        const double rem = (double)(psz[0] - npe[0]);
        double2 rl = *(const double2*)&Wta[128 * 128 + o0];
        double2 rh = *(const double2*)&Wta[128 * 128 + 64 + o0];
        const double ad[4] = {
            rl.x * rem + (double)b_a[o0],
            rl.y * rem + (double)b_a[o0 + 1],
            rh.x * rem + (double)b_a[64 + o0],
            rh.y * rem + (double)b_a[64 + o0 + 1] };
        __syncthreads();   // all reads of sX done
        #pragma unroll
        for (int i = 0; i < 4; i++) {
            int o = (i < 2) ? (o0 + i) : (64 + o0 + i - 2);
            #pragma unroll
            for (int j = 0; j < 4; j++) {
                double2 v = { fmax(acc[i][2*j] + ad[i], 0.0),
                              fmax(acc[i][2*j+1] + ad[i], 0.0) };
                *(double2*)&sX[o * AST + n0 + 2 * j] = v;
            }
        }
    }
    __syncthreads();

    // ---- phase 4: xb = relu(w_b @ xa + b_b), in-place (rows 0..63)
    {
        double acc[2][8] = {};
        const double* __restrict__ wk = &Wtb[o0];
        const double* __restrict__ ak = &sX[n0];
        double2 wc = *(const double2*)&wk[0];
        double2 wd = *(const double2*)&wk[64];
        double2 ac[4];
        #pragma unroll
        for (int i = 0; i < 4; i++) ac[i] = *(const double2*)&ak[2 * i];
        #pragma unroll 4
        for (int k = 0; k < 128; k++) {
            const int k1 = (k + 1) & 127;
            const int k2 = (k + 2) & 127;
            double2 wn = *(const double2*)&wk[k2 * 64];
            double2 an[4];
            #pragma unroll
            for (int i = 0; i < 4; i++)
                an[i] = *(const double2*)&ak[k1 * AST + 2 * i];
            #pragma unroll
            for (int i = 0; i < 4; i++) {
                acc[0][2*i]   += wc.x * ac[i].x; acc[0][2*i+1] += wc.x * ac[i].y;
                acc[1][2*i]   += wc.y * ac[i].x; acc[1][2*i+1] += wc.y * ac[i].y;
            }
            wc = wd; wd = wn;
            #pragma unroll
            for (int i = 0; i < 4; i++) ac[i] = an[i];
        }
        __syncthreads();   // all reads of sX done
        #pragma unroll
        for (int i = 0; i < 2; i++) {
            int o = o0 + i;
            double bb = (double)b_b[o];
            #pragma unroll
            for (int j = 0; j < 4; j++) {
                double2 v = { fmax(acc[i][2*j] + bb, 0.0),
                              fmax(acc[i][2*j+1] + bb, 0.0) };
                *(double2*)&sX[o * AST + n0 + 2 * j] = v;
            }
        }
    }
    __syncthreads();

    // ---- phase 5: score = w_c . xb + b_c (4 thr/node, 64 nodes)
    //      + block max -> atomicMax(gmaxu)
    {
        const int j4 = tid & 3, ns = tid >> 2;      // ns 0..63
        double v = 0.0;
        #pragma unroll
        for (int r = 0; r < 16; r++)
            v += (double)w_c[j4 + 4 * r] * sX[(j4 + 4 * r) * AST + ns];
        v += __shfl_down(v, 2);
        v += __shfl_down(v, 1);
        double sc = v + (double)b_c[0];
        const bool valid = (base + ns) < N_NODES;
        if (j4 == 0 && valid)
            scoresd[base + ns] = sc;
        // block max of final scores (invalid/other lanes masked to -inf)
        double vh = (j4 == 0 && valid) ? sc : -HUGE_VAL;
        #pragma unroll
        for (int off = 32; off > 0; off >>= 1)
            vh = fmax(vh, __shfl_down(vh, off));
        if ((tid & 63) == 0) sS[tid >> 6] = vh;
        __syncthreads();
        if (tid == 0)
            atomicMax(gmaxu, dkey(fmax(fmax(sS[0], sS[1]),
                                       fmax(sS[2], sS[3]))));
    }
}

// ---------------- kernel 3: fused softmax (exp + sum + scale), persistent.
// r26: replaces exp_sum + scale. 196 blocks (<= 256 CUs -> all co-resident;
// no LDS/VGPR pressure), each thread owns <=2 elements kept in registers.
// Protocol: block partial sum -> atomicAdd(gsum) -> threadfence -> done++ ;
// spin until done == SM_BLOCKS (device-scope atomics are cross-XCD coherent,
// G16); then invS = 1/gsum and write out from registers. Saves one launch
// gap and one full re-read of the exp array.
__global__ __launch_bounds__(256) void softmax_kernel(
    const double* __restrict__ s, const unsigned long long* __restrict__ gmaxu,
    double* __restrict__ gsum, int* __restrict__ done,
    float* __restrict__ out)
{
    __shared__ double red[4];
    __shared__ double sinv;
    const int tid = threadIdx.x;
    const double m = dunkey(gmaxu[0]);
    const int i0 = blockIdx.x * 256 + tid;
    const int i1 = i0 + SM_BLOCKS * 256;            // 50176 stride

    double e0 = 0.0, e1 = 0.0, acc = 0.0;
    if (i0 < N_NODES) { e0 = exp(s[i0] - m); acc += e0; }
    if (i1 < N_NODES) { e1 = exp(s[i1] - m); acc += e1; }

    #pragma unroll
    for (int off = 32; off > 0; off >>= 1) acc += __shfl_down(acc, off);
    if ((tid & 63) == 0) red[tid >> 6] = acc;
    __syncthreads();
    if (tid == 0) {
        atomicAdd(gsum, (red[0] + red[1]) + (red[2] + red[3]));
        __threadfence();                             // sum visible before done++
        atomicAdd(done, 1);
        while (__hip_atomic_load(done, __ATOMIC_RELAXED,
                                 __HIP_MEMORY_SCOPE_AGENT) < SM_BLOCKS) {
            __builtin_amdgcn_s_sleep(1);
        }
        __threadfence();
        sinv = 1.0 / __hip_atomic_load(gsum, __ATOMIC_RELAXED,
                                       __HIP_MEMORY_SCOPE_AGENT);
    }
    __syncthreads();
    const double invS = sinv;
    if (i0 < N_NODES) out[i0] = (float)(e0 * invS);
    if (i1 < N_NODES) out[i1] = (float)(e1 * invS);
}

// ---------------- launch ----------------
extern "C" void kernel_launch(void* const* d_in, const int* in_sizes, int n_in,
                              void* d_out, int out_size, void* d_ws, size_t ws_size,
                              hipStream_t stream)
{
    const int*   nodes = (const int*)  d_in[0];
    const float* feat  = (const float*)d_in[1];
    const int*   n1    = (const int*)  d_in[2];
    const int*   n2    = (const int*)  d_in[3];
    const float* W1    = (const float*)d_in[4];
    const float* W2    = (const float*)d_in[5];
    const float* w_a   = (const float*)d_in[6];
    const float* b_a   = (const float*)d_in[7];
    const float* w_b   = (const float*)d_in[8];
    const float* b_b   = (const float*)d_in[9];
    const float* w_c   = (const float*)d_in[10];
    const float* b_c   = (const float*)d_in[11];
    const int*   psz   = (const int*)  d_in[12];
    const int*   npe   = (const int*)  d_in[13];
    float* out = (float*)d_out;

    double* agg1d   = (double*)d_ws;                       // 300000 doubles
    double* scoresd = agg1d + (size_t)N_NODES * 3;         // 100000
    unsigned long long* gmaxu =
        (unsigned long long*)(scoresd + N_NODES);          // 1 (8B)
    double* gsum    = (double*)(gmaxu + 1);                // 1
    int*    done    = (int*)(gsum + 1);                    // 1 (4B)
    double* wt      = scoresd + N_NODES + 16;              // PAD_ELEMS, 16B-aligned
    float4* feat4   = (float4*)(wt + PAD_ELEMS);           // 100000 float4 (16B-al.)

    const int pack_blocks = (PAD_ELEMS + N_NODES + 255) / 256;   // 552
    pack_kernel<<<pack_blocks, 256, 0, stream>>>(
        feat, W2, w_a, w_b, wt, feat4, gmaxu, gsum, done);
    gather_kernel<<<(N_NODES + 63) / 64, 64, 0, stream>>>(feat4, n1, agg1d);
    enc2_mlp_kernel<<<(N_NODES + NT - 1) / NT, 256, 0, stream>>>(
        nodes, n2, agg1d, W1, wt, b_a, b_b, w_c, b_c, psz, npe, scoresd, gmaxu);
    softmax_kernel<<<SM_BLOCKS, 256, 0, stream>>>(scoresd, gmaxu, gsum, done, out);
}

// Round 15
// 355.041 us; speedup vs baseline: 1.0361x; 1.0361x over previous
//
#include <hip/hip_runtime.h>
#include <math.h>

#define N_NODES 100000
#define S1 50
#define S2 10
#define HID 128
#define NT 64          // nodes per block in enc2_mlp
#define AST 66         // act row stride in doubles ([k][n] rows, 16B-aligned)

// transposed fp64 weight sizes
#define W2_ELEMS   (128 * 128)     // Wt2[k][o]
#define WA_ELEMS   (129 * 128)     // Wta[k][o], k=128 row = remaining-space col
#define WB_ELEMS   (128 * 64)      // Wtb[k][o]
#define PAD_ELEMS  (W2_ELEMS + WA_ELEMS + WB_ELEMS)   // 41088

// monotone u64 key for fp64 atomicMax (finite doubles)
__device__ __forceinline__ unsigned long long dkey(double d) {
    unsigned long long u = __double_as_longlong(d);
    return (u & 0x8000000000000000ULL) ? ~u : (u | 0x8000000000000000ULL);
}
__device__ __forceinline__ double dunkey(unsigned long long k) {
    return (k & 0x8000000000000000ULL)
        ? __longlong_as_double(k & 0x7FFFFFFFFFFFFFFFULL)
        : __longlong_as_double(~k);
}

// ---------------- kernel 0: weight transpose + feat->float4 pack + scalar init
__global__ __launch_bounds__(256) void pack_kernel(
    const float* __restrict__ feat,
    const float* __restrict__ W2, const float* __restrict__ w_a,
    const float* __restrict__ w_b,
    double* __restrict__ wt, float4* __restrict__ feat4,
    unsigned long long* __restrict__ gmaxu, double* __restrict__ gsum)
{
    int i = blockIdx.x * 256 + threadIdx.x;
    if (i == 0) { gmaxu[0] = 0ULL; gsum[0] = 0.0; }   // key(finite) > 0 always
    if (i < W2_ELEMS) {
        int k = i >> 7, o = i & 127;
        wt[i] = (double)W2[o * 128 + k];
    } else if (i < W2_ELEMS + WA_ELEMS) {
        int j = i - W2_ELEMS;
        int k = j >> 7, o = j & 127;
        wt[i] = (double)w_a[o * 129 + k];
    } else if (i < PAD_ELEMS) {
        int j = i - W2_ELEMS - WA_ELEMS;
        int k = j >> 6, o = j & 63;
        wt[i] = (double)w_b[o * 128 + k];
    } else if (i < PAD_ELEMS + N_NODES) {
        int n = i - PAD_ELEMS;
        float4 v = { feat[n * 3 + 0], feat[n * 3 + 1], feat[n * 3 + 2], 0.0f };
        feat4[n] = v;
    }
}

// ---------------- kernel 1: agg1 (fp64), one node per thread.
// r27 = r25 exact revert (measured best: total 357.6). r26's int2 index
// loads + persistent fused softmax REGRESSED +10us (spin barrier costs more
// than the launch gap; gather is request-bound, not instruction-bound).
__global__ __launch_bounds__(64) void gather_kernel(
    const float4* __restrict__ feat4, const int* __restrict__ neigh1,
    double* __restrict__ agg1d)
{
    const int n = blockIdx.x * 64 + threadIdx.x;
    if (n >= N_NODES) return;
    const int* __restrict__ row = &neigh1[n * S1];
    double f0, f1, f2;
    { float4 v = feat4[n]; f0 = (double)v.x; f1 = (double)v.y; f2 = (double)v.z; }
    #pragma unroll 10
    for (int j = 0; j < S1; j++) {
        float4 v = feat4[row[j]];
        f0 += (double)v.x; f1 += (double)v.y; f2 += (double)v.z;
    }
    const double r51 = 1.0 / 51.0;
    agg1d[n * 3 + 0] = f0 * r51;
    agg1d[n * 3 + 1] = f1 * r51;
    agg1d[n * 3 + 2] = f2 * r51;
}

// ---------------- kernel 2: enc2 + MLP + score, fp64, software-pipelined.
// FROZEN at r23 (268 us measured; the per-thread hot-loop core is the
// r15 shape that six structural variants failed to beat).
__global__ __launch_bounds__(256, 1) void enc2_mlp_kernel(
    const int* __restrict__ nodes, const int* __restrict__ neigh2,
    const double* __restrict__ agg1d,
    const float* __restrict__ W1, const double* __restrict__ wt,
    const float* __restrict__ b_a, const float* __restrict__ b_b,
    const float* __restrict__ w_c, const float* __restrict__ b_c,
    const int* __restrict__ psz, const int* __restrict__ npe,
    double* __restrict__ scoresd, unsigned long long* __restrict__ gmaxu)
{
    __shared__ __align__(16) double sX[HID * AST];      // 67584 B, acts [k][n]
    __shared__ double sS[4];
    double* sG = sX;   // gathered agg1 rows, NT*11*4 = 2816 doubles (22528 B),
                       // aliases sX rows 0..42 -- dead before first sX write

    const double* __restrict__ Wt2 = wt;
    const double* __restrict__ Wta = wt + W2_ELEMS;
    const double* __restrict__ Wtb = wt + W2_ELEMS + WA_ELEMS;

    const int tid  = threadIdx.x;
    const int base = blockIdx.x * NT;               // 1563 blocks, last partial

    // ---- phase 0: gather 11 agg1 rows per node into sG (704 items)
    for (int t = tid; t < NT * (S2 + 1); t += 256) {
        int ns = t / 11, j = t - ns * 11;
        int gi = base + ns;
        int node = nodes[gi < N_NODES ? gi : N_NODES - 1];  // tail clamp
        int src  = (j == 0) ? node : neigh2[node * S2 + (j - 1)];
        sG[t * 4 + 0] = agg1d[src * 3 + 0];
        sG[t * 4 + 1] = agg1d[src * 3 + 1];
        sG[t * 4 + 2] = agg1d[src * 3 + 2];
    }
    __syncthreads();

    // ---- phase 1: agg2[t][n] = mean_j relu(W1[t].row_j) -> sX[t*AST+n]
    {
        const int n = tid & 63;
        double g0[11], g1[11], g2[11];
        #pragma unroll
        for (int j = 0; j < 11; j++) {
            g0[j] = sG[(n * 11 + j) * 4 + 0];
            g1[j] = sG[(n * 11 + j) * 4 + 1];
            g2[j] = sG[(n * 11 + j) * 4 + 2];
        }
        __syncthreads();   // sG fully consumed into registers; sX may be written
        const int part = tid >> 6;                  // 0..3
        #pragma unroll
        for (int s = 0; s < 32; s++) {
            int t = part * 32 + s;
            double wx = (double)W1[t * 3 + 0];
            double wy = (double)W1[t * 3 + 1];
            double wz = (double)W1[t * 3 + 2];
            double acc = 0.0;
            #pragma unroll
            for (int j = 0; j < 11; j++)
                acc += fmax(wx * g0[j] + wy * g1[j] + wz * g2[j], 0.0);
            sX[t * AST + n] = acc / 11.0;
        }
    }
    __syncthreads();

    const int og = tid & 31;          // 0..31
    const int ng = tid >> 5;          // 0..7
    const int n0 = 8 * ng;            // 8 node cols per thread (64 total)
    const int o0 = 2 * og;            // outs o0, o0+1, 64+o0, 64+o0+1

    // ---- phase 2: emb = relu(W2 @ agg2), in-place sX
    {
        double acc[4][8] = {};
        const double* __restrict__ wk = &Wt2[o0];
        const double* __restrict__ ak = &sX[n0];
        // pipeline primers: weights k=0 (current) and k=1 (next); acts k=0
        double2 wc0 = *(const double2*)&wk[0];
        double2 wc1 = *(const double2*)&wk[64];
        double2 wd0 = *(const double2*)&wk[128];
        double2 wd1 = *(const double2*)&wk[128 + 64];
        double2 ac[4];
        #pragma unroll
        for (int i = 0; i < 4; i++) ac[i] = *(const double2*)&ak[2 * i];
        #pragma unroll 4
        for (int k = 0; k < 128; k++) {
            const int k1 = (k + 1) & 127;
            const int k2 = (k + 2) & 127;
            double2 wn0 = *(const double2*)&wk[k2 * 128];
            double2 wn1 = *(const double2*)&wk[k2 * 128 + 64];
            double2 an[4];
            #pragma unroll
            for (int i = 0; i < 4; i++)
                an[i] = *(const double2*)&ak[k1 * AST + 2 * i];
            #pragma unroll
            for (int i = 0; i < 4; i++) {
                acc[0][2*i]   += wc0.x * ac[i].x; acc[0][2*i+1] += wc0.x * ac[i].y;
                acc[1][2*i]   += wc0.y * ac[i].x; acc[1][2*i+1] += wc0.y * ac[i].y;
                acc[2][2*i]   += wc1.x * ac[i].x; acc[2][2*i+1] += wc1.x * ac[i].y;
                acc[3][2*i]   += wc1.y * ac[i].x; acc[3][2*i+1] += wc1.y * ac[i].y;
            }
            wc0 = wd0; wc1 = wd1; wd0 = wn0; wd1 = wn1;
            #pragma unroll
            for (int i = 0; i < 4; i++) ac[i] = an[i];
        }
        __syncthreads();   // all reads of sX done
        #pragma unroll
        for (int i = 0; i < 4; i++) {
            int o = (i < 2) ? (o0 + i) : (64 + o0 + i - 2);
            #pragma unroll
            for (int j = 0; j < 4; j++) {
                double2 v = { fmax(acc[i][2*j], 0.0), fmax(acc[i][2*j+1], 0.0) };
                *(double2*)&sX[o * AST + n0 + 2 * j] = v;
            }
        }
    }
    __syncthreads();

    // ---- phase 3: xa = relu(w_a[:,:128] @ emb + w_a[:,128]*rem + b_a), in-place
    {
        double acc[4][8] = {};
        const double* __restrict__ wk = &Wta[o0];
        const double* __restrict__ ak = &sX[n0];
        double2 wc0 = *(const double2*)&wk[0];
        double2 wc1 = *(const double2*)&wk[64];
        double2 wd0 = *(const double2*)&wk[128];
        double2 wd1 = *(const double2*)&wk[128 + 64];
        double2 ac[4];
        #pragma unroll
        for (int i = 0; i < 4; i++) ac[i] = *(const double2*)&ak[2 * i];
        #pragma unroll 4
        for (int k = 0; k < 128; k++) {
            const int k1 = (k + 1) & 127;
            const int k2 = (k + 2) & 127;
            double2 wn0 = *(const double2*)&wk[k2 * 128];
            double2 wn1 = *(const double2*)&wk[k2 * 128 + 64];
            double2 an[4];
            #pragma unroll
            for (int i = 0; i < 4; i++)
                an[i] = *(const double2*)&ak[k1 * AST + 2 * i];
            #pragma unroll
            for (int i = 0; i < 4; i++) {
                acc[0][2*i]   += wc0.x * ac[i].x; acc[0][2*i+1] += wc0.x * ac[i].y;
                acc[1][2*i]   += wc0.y * ac[i].x; acc[1][2*i+1] += wc0.y * ac[i].y;
                acc[2][2*i]   += wc1.x * ac[i].x; acc[2][2*i+1] += wc1.x * ac[i].y;
                acc[3][2*i]   += wc1.y * ac[i].x; acc[3][2*i+1] += wc1.y * ac[i].y;
            }
            wc0 = wd0; wc1 = wd1; wd0 = wn0; wd1 = wn1;
            #pragma unroll
            for (int i = 0; i < 4; i++) ac[i] = an[i];
        }
        const double rem = (double)(psz[0] - npe[0]);
        double2 rl = *(const double2*)&Wta[128 * 128 + o0];
        double2 rh = *(const double2*)&Wta[128 * 128 + 64 + o0];
        const double ad[4] = {
            rl.x * rem + (double)b_a[o0],
            rl.y * rem + (double)b_a[o0 + 1],
            rh.x * rem + (double)b_a[64 + o0],
            rh.y * rem + (double)b_a[64 + o0 + 1] };
        __syncthreads();   // all reads of sX done
        #pragma unroll
        for (int i = 0; i < 4; i++) {
            int o = (i < 2) ? (o0 + i) : (64 + o0 + i - 2);
            #pragma unroll
            for (int j = 0; j < 4; j++) {
                double2 v = { fmax(acc[i][2*j] + ad[i], 0.0),
                              fmax(acc[i][2*j+1] + ad[i], 0.0) };
                *(double2*)&sX[o * AST + n0 + 2 * j] = v;
            }
        }
    }
    __syncthreads();

    // ---- phase 4: xb = relu(w_b @ xa + b_b), in-place (rows 0..63)
    {
        double acc[2][8] = {};
        const double* __restrict__ wk = &Wtb[o0];
        const double* __restrict__ ak = &sX[n0];
        double2 wc = *(const double2*)&wk[0];
        double2 wd = *(const double2*)&wk[64];
        double2 ac[4];
        #pragma unroll
        for (int i = 0; i < 4; i++) ac[i] = *(const double2*)&ak[2 * i];
        #pragma unroll 4
        for (int k = 0; k < 128; k++) {
            const int k1 = (k + 1) & 127;
            const int k2 = (k + 2) & 127;
            double2 wn = *(const double2*)&wk[k2 * 64];
            double2 an[4];
            #pragma unroll
            for (int i = 0; i < 4; i++)
                an[i] = *(const double2*)&ak[k1 * AST + 2 * i];
            #pragma unroll
            for (int i = 0; i < 4; i++) {
                acc[0][2*i]   += wc.x * ac[i].x; acc[0][2*i+1] += wc.x * ac[i].y;
                acc[1][2*i]   += wc.y * ac[i].x; acc[1][2*i+1] += wc.y * ac[i].y;
            }
            wc = wd; wd = wn;
            #pragma unroll
            for (int i = 0; i < 4; i++) ac[i] = an[i];
        }
        __syncthreads();   // all reads of sX done
        #pragma unroll
        for (int i = 0; i < 2; i++) {
            int o = o0 + i;
            double bb = (double)b_b[o];
            #pragma unroll
            for (int j = 0; j < 4; j++) {
                double2 v = { fmax(acc[i][2*j] + bb, 0.0),
                              fmax(acc[i][2*j+1] + bb, 0.0) };
                *(double2*)&sX[o * AST + n0 + 2 * j] = v;
            }
        }
    }
    __syncthreads();

    // ---- phase 5: score = w_c . xb + b_c (4 thr/node, 64 nodes)
    //      + block max -> atomicMax(gmaxu)
    {
        const int j4 = tid & 3, ns = tid >> 2;      // ns 0..63
        double v = 0.0;
        #pragma unroll
        for (int r = 0; r < 16; r++)
            v += (double)w_c[j4 + 4 * r] * sX[(j4 + 4 * r) * AST + ns];
        v += __shfl_down(v, 2);
        v += __shfl_down(v, 1);
        double sc = v + (double)b_c[0];
        const bool valid = (base + ns) < N_NODES;
        if (j4 == 0 && valid)
            scoresd[base + ns] = sc;
        // block max of final scores (invalid/other lanes masked to -inf)
        double vh = (j4 == 0 && valid) ? sc : -HUGE_VAL;
        #pragma unroll
        for (int off = 32; off > 0; off >>= 1)
            vh = fmax(vh, __shfl_down(vh, off));
        if ((tid & 63) == 0) sS[tid >> 6] = vh;
        __syncthreads();
        if (tid == 0)
            atomicMax(gmaxu, dkey(fmax(fmax(sS[0], sS[1]),
                                       fmax(sS[2], sS[3]))));
    }
}

// ---------------- softmax: 2 kernels (max came from enc2's atomicMax) -------
__global__ __launch_bounds__(256) void exp_sum_kernel(
    double* __restrict__ s, const unsigned long long* __restrict__ gmaxu,
    double* __restrict__ gsum)
{
    __shared__ double red[4];
    const int tid = threadIdx.x;
    const double m = dunkey(gmaxu[0]);

    double acc = 0.0;
    for (int i = blockIdx.x * 256 + tid; i < N_NODES; i += gridDim.x * 256) {
        double e = exp(s[i] - m);
        s[i] = e;
        acc += e;
    }
    #pragma unroll
    for (int off = 32; off > 0; off >>= 1) acc += __shfl_down(acc, off);
    if ((tid & 63) == 0) red[tid >> 6] = acc;
    __syncthreads();
    if (tid == 0)
        atomicAdd(gsum, (red[0] + red[1]) + (red[2] + red[3]));
}

__global__ __launch_bounds__(256) void scale_kernel(
    const double* __restrict__ e, const double* __restrict__ gsum,
    float* __restrict__ out)
{
    __shared__ double sv;
    const int tid = threadIdx.x;
    if (tid == 0) sv = 1.0 / gsum[0];
    __syncthreads();
    const int i = blockIdx.x * 256 + tid;
    if (i < N_NODES) out[i] = (float)(e[i] * sv);
}

// ---------------- launch ----------------
extern "C" void kernel_launch(void* const* d_in, const int* in_sizes, int n_in,
                              void* d_out, int out_size, void* d_ws, size_t ws_size,
                              hipStream_t stream)
{
    const int*   nodes = (const int*)  d_in[0];
    const float* feat  = (const float*)d_in[1];
    const int*   n1    = (const int*)  d_in[2];
    const int*   n2    = (const int*)  d_in[3];
    const float* W1    = (const float*)d_in[4];
    const float* W2    = (const float*)d_in[5];
    const float* w_a   = (const float*)d_in[6];
    const float* b_a   = (const float*)d_in[7];
    const float* w_b   = (const float*)d_in[8];
    const float* b_b   = (const float*)d_in[9];
    const float* w_c   = (const float*)d_in[10];
    const float* b_c   = (const float*)d_in[11];
    const int*   psz   = (const int*)  d_in[12];
    const int*   npe   = (const int*)  d_in[13];
    float* out = (float*)d_out;

    double* agg1d   = (double*)d_ws;                       // 300000 doubles
    double* scoresd = agg1d + (size_t)N_NODES * 3;         // 100000
    unsigned long long* gmaxu =
        (unsigned long long*)(scoresd + N_NODES);          // 1 (8B)
    double* gsum    = (double*)(gmaxu + 1);                // 1
    double* wt      = scoresd + N_NODES + 16;              // PAD_ELEMS, 16B-aligned
    float4* feat4   = (float4*)(wt + PAD_ELEMS);           // 100000 float4 (16B-al.)

    const int pack_blocks = (PAD_ELEMS + N_NODES + 255) / 256;   // 552
    pack_kernel<<<pack_blocks, 256, 0, stream>>>(
        feat, W2, w_a, w_b, wt, feat4, gmaxu, gsum);
    gather_kernel<<<(N_NODES + 63) / 64, 64, 0, stream>>>(feat4, n1, agg1d);
    enc2_mlp_kernel<<<(N_NODES + NT - 1) / NT, 256, 0, stream>>>(
        nodes, n2, agg1d, W1, wt, b_a, b_b, w_c, b_c, psz, npe, scoresd, gmaxu);
    exp_sum_kernel<<<256, 256, 0, stream>>>(scoresd, gmaxu, gsum);
    scale_kernel<<<(N_NODES + 255) / 256, 256, 0, stream>>>(scoresd, gsum, out);
}